// Round 17
// baseline (440.221 us; speedup 1.0000x reference)
//
#include <hip/hip_runtime.h>

typedef __bf16 bf16;
typedef __attribute__((ext_vector_type(8))) __bf16 bf16x8;
typedef __attribute__((ext_vector_type(4))) float f32x4;

#define HH 256
#define WW 256
#define BB 4
#define NPIX 65536
#define AS 264              // act stride (halo 4)
#define APX 69696           // AS*AS

#define GLOAD16(SRC, DST) __builtin_amdgcn_global_load_lds( \
    (const __attribute__((address_space(1))) void*)(SRC),   \
    (__attribute__((address_space(3))) void*)(DST), 16, 0, 0)

__device__ inline bf16x8 bzero8() {
    bf16x8 v;
    #pragma unroll
    for (int i = 0; i < 8; ++i) v[i] = (bf16)0.0f;
    return v;
}

// slot s <-> true channel ch(s)
__device__ inline int chof(int s) {
    return 4 * (s >> 3) + 16 * ((s >> 2) & 1) + (s & 3);
}

// ---------------------------------------------------------------------------
// input NCHW fp32 -> in0b (haloed NHWC bf16, SLOT-permuted channels)
// ---------------------------------------------------------------------------
__global__ __launch_bounds__(256) void prep_in(const float* __restrict__ in,
                                               bf16* __restrict__ outP) {
    int p = blockIdx.x * 256 + threadIdx.x;
    int b = p >> 16, rem = p & 65535;
    int y = rem >> 8, x = rem & 255;
    float ch[32];
    #pragma unroll
    for (int c = 0; c < 32; ++c)
        ch[c] = in[(size_t)(b * 32 + c) * NPIX + rem];
    bf16* o = outP + ((size_t)b * APX + (size_t)(y + 4) * AS + x + 4) * 32;
    #pragma unroll
    for (int g = 0; g < 4; ++g) {
        bf16x8 w;
        #pragma unroll
        for (int j = 0; j < 4; ++j) {
            w[j]     = (bf16)ch[4 * g + j];
            w[4 + j] = (bf16)ch[16 + 4 * g + j];
        }
        *reinterpret_cast<bf16x8*>(o + g * 8) = w;
    }
}

// ---------------------------------------------------------------------------
// zero the halos of in0b/actA/actB (4160 px each per batch)
// ---------------------------------------------------------------------------
__global__ __launch_bounds__(256) void zero_halo(bf16* __restrict__ in0b,
                                                 bf16* __restrict__ actA,
                                                 bf16* __restrict__ actB) {
    int i = blockIdx.x * 256 + threadIdx.x;
    const int NA = 3 * 4 * 4160;
    if (i < NA) {
        int buf = i / (4 * 4160), r = i % (4 * 4160);
        int b = r / 4160, k = r % 4160;
        int y, x;
        if (k < 2112) { int rr = k / 264; y = rr < 4 ? rr : 256 + rr; x = k % 264; }
        else { int j = k - 2112; y = 4 + j / 8; int c8 = j % 8; x = c8 < 4 ? c8 : 256 + c8; }
        bf16* p = (buf == 0 ? in0b : buf == 1 ? actA : actB) +
                  ((size_t)b * APX + (size_t)y * AS + x) * 32;
        #pragma unroll
        for (int cg = 0; cg < 4; ++cg)
            *reinterpret_cast<bf16x8*>(p + cg * 8) = bzero8();
    }
}

// ---------------------------------------------------------------------------
// Fold BN into conv weights. All activation ci dims are SLOT-permuted.
// ---------------------------------------------------------------------------
__global__ void fold_w(const float* __restrict__ wconv, const float* __restrict__ bconv,
                       const float* __restrict__ g, const float* __restrict__ beta,
                       const float* __restrict__ mu, const float* __restrict__ var,
                       const float* __restrict__ w_outc, const float* __restrict__ b_outc,
                       const float* __restrict__ w_final, const float* __restrict__ tau,
                       bf16* __restrict__ Wres, float* __restrict__ Bres,
                       bf16* __restrict__ Wcore, bf16* __restrict__ Wfin,
                       float* __restrict__ bCore, float* __restrict__ tauP) {
    int idx = blockIdx.x * 256 + threadIdx.x;
    if (idx < 73728) {
        int l = idx / 9216, r = idx % 9216;
        int tap = r >> 10, co = (r >> 5) & 31, ci = chof(r & 31);
        float s = g[l * 32 + co] * rsqrtf(var[l * 32 + co] + 1e-5f);
        Wres[idx] = (bf16)(wconv[l * 9216 + (co * 32 + ci) * 9 + tap] * s);
    } else if (idx < 73984) {
        int i = idx - 73728;
        float s = g[i] * rsqrtf(var[i] + 1e-5f);
        Bres[i] = (bconv[i] - mu[i]) * s + beta[i];
    } else if (idx < 83200) {
        int r = idx - 73984;
        int tap = r >> 10, nn = (r >> 5) & 31, ci = chof(r & 31);
        Wcore[r] = (bf16)w_outc[(nn * 9 + tap) * 32 + ci];
    } else if (idx < 120064) {
        int r = idx - 83200;
        int chunk = r / 9216, r2 = r % 9216;
        int tap = r2 >> 10, co = (r2 >> 5) & 31, n = chof(r2 & 31);
        Wfin[r] = (bf16)w_final[(size_t)(co * 128 + chunk * 32 + n) * 9 + tap];
    } else if (idx < 120352) {
        int r = idx - 120064;       // tap*32 + n
        int tap = r >> 5, n = r & 31;
        bCore[r] = b_outc[n * 9 + tap];
    } else if (idx < 120384) {
        int s = idx - 120352;
        tauP[s] = tau[chof(s)];
    }
}

// ---------------------------------------------------------------------------
// Fused residual block v4 (r14-proven): dy-blocked, gload+swizzle staging.
// ---------------------------------------------------------------------------
__global__ __launch_bounds__(512) void resblock_v4(
    const bf16* __restrict__ in, const bf16* __restrict__ W1,
    const bf16* __restrict__ W2, const float* __restrict__ B1,
    const float* __restrict__ B2, bf16* __restrict__ out) {
    extern __shared__ char smem[];
    bf16* xs = (bf16*)smem;             // [12][68] records, 64 B each, swizzled
    bf16* hs = (bf16*)(smem + 52224);   // [10][66] records, pitch 40 el
    const int x0 = blockIdx.x * 64, y0 = blockIdx.y * 8, b = blockIdx.z;
    const int tid = threadIdx.x;
    const int lane = tid & 63, wv = tid >> 6;
    const int col = lane & 15, g = lane >> 4;
    const bf16* inb = in + (size_t)b * APX * 32;

    for (int gi = wv; gi < 51; gi += 8) {
        int i = gi * 64 + lane;
        int px = i >> 2, s = i & 3;
        int yy = px / 68, xx = px % 68;
        int gsl = s ^ ((px >> 1) & 3);
        const bf16* src = inb + ((size_t)(y0 + yy + 2) * AS + x0 + xx + 2) * 32 + gsl * 8;
        GLOAD16(src, smem + gi * 1024);
    }

    bf16x8 Wf[9][2];
    #pragma unroll
    for (int tap = 0; tap < 9; ++tap) {
        Wf[tap][0] = *reinterpret_cast<const bf16x8*>(W1 + tap * 1024 + col * 32 + g * 8);
        Wf[tap][1] = *reinterpret_cast<const bf16x8*>(W1 + tap * 1024 + (16 + col) * 32 + g * 8);
    }
    f32x4 bb0 = *reinterpret_cast<const f32x4*>(B1 + 4 * g);
    f32x4 bb1 = *reinterpret_cast<const f32x4*>(B1 + 16 + 4 * g);
    __syncthreads();

    for (int id = wv; id < 15; id += 8) {
        int u = id / 5, s5 = id % 5;
        int rb = u * 4; if (rb > 6) rb = 6;
        int off = s5 * 16; if (off > 50) off = 50;
        f32x4 c[4][2];
        #pragma unroll
        for (int rr = 0; rr < 4; ++rr) { c[rr][0] = bb0; c[rr][1] = bb1; }
        #pragma unroll
        for (int d = 0; d < 6; ++d) {
            #pragma unroll
            for (int dx = 0; dx < 3; ++dx) {
                const int px = (rb + d) * 68 + off + col + dx;
                bf16x8 Bf = *reinterpret_cast<const bf16x8*>(
                    xs + px * 32 + (g ^ ((px >> 1) & 3)) * 8);
                #pragma unroll
                for (int rr = 0; rr < 4; ++rr) {
                    if (rr <= d && d - rr <= 2) {
                        const int tap = (d - rr) * 3 + dx;
                        c[rr][0] = __builtin_amdgcn_mfma_f32_16x16x32_bf16(Wf[tap][0], Bf, c[rr][0], 0, 0, 0);
                        c[rr][1] = __builtin_amdgcn_mfma_f32_16x16x32_bf16(Wf[tap][1], Bf, c[rr][1], 0, 0, 0);
                    }
                }
            }
        }
        #pragma unroll
        for (int rr = 0; rr < 4; ++rr) {
            bf16x8 o;
            #pragma unroll
            for (int j = 0; j < 4; ++j) {
                o[j]     = (bf16)fmaxf(c[rr][0][j], 0.0f);
                o[4 + j] = (bf16)fmaxf(c[rr][1][j], 0.0f);
            }
            const int hy = y0 + rb + rr - 1;
            const int hx = x0 + off + col - 1;
            if ((unsigned)hy >= HH || (unsigned)hx >= WW) o = bzero8();
            *reinterpret_cast<bf16x8*>(hs + ((rb + rr) * 66 + off + col) * 40 + g * 8) = o;
        }
    }

    #pragma unroll
    for (int tap = 0; tap < 9; ++tap) {
        Wf[tap][0] = *reinterpret_cast<const bf16x8*>(W2 + tap * 1024 + col * 32 + g * 8);
        Wf[tap][1] = *reinterpret_cast<const bf16x8*>(W2 + tap * 1024 + (16 + col) * 32 + g * 8);
    }
    bb0 = *reinterpret_cast<const f32x4*>(B2 + 4 * g);
    bb1 = *reinterpret_cast<const f32x4*>(B2 + 16 + 4 * g);
    __syncthreads();

    {
        const int rb2 = (wv >> 2) * 4, seg = (wv & 3) * 16;
        f32x4 c[4][2];
        #pragma unroll
        for (int rr = 0; rr < 4; ++rr) { c[rr][0] = bb0; c[rr][1] = bb1; }
        #pragma unroll
        for (int d = 0; d < 6; ++d) {
            #pragma unroll
            for (int dx = 0; dx < 3; ++dx) {
                bf16x8 Bf = *reinterpret_cast<const bf16x8*>(
                    hs + ((rb2 + d) * 66 + seg + col + dx) * 40 + g * 8);
                #pragma unroll
                for (int rr = 0; rr < 4; ++rr) {
                    if (rr <= d && d - rr <= 2) {
                        const int tap = (d - rr) * 3 + dx;
                        c[rr][0] = __builtin_amdgcn_mfma_f32_16x16x32_bf16(Wf[tap][0], Bf, c[rr][0], 0, 0, 0);
                        c[rr][1] = __builtin_amdgcn_mfma_f32_16x16x32_bf16(Wf[tap][1], Bf, c[rr][1], 0, 0, 0);
                    }
                }
            }
        }
        bf16* outb = out + (size_t)b * APX * 32;
        #pragma unroll
        for (int rr = 0; rr < 4; ++rr) {
            const int y = rb2 + rr;
            const int pxr = (y + 2) * 68 + seg + col + 2;
            bf16x8 xr = *reinterpret_cast<const bf16x8*>(
                xs + pxr * 32 + (g ^ ((pxr >> 1) & 3)) * 8);
            bf16x8 o;
            #pragma unroll
            for (int j = 0; j < 4; ++j) {
                o[j]     = (bf16)fmaxf(c[rr][0][j] + (float)xr[j], 0.0f);
                o[4 + j] = (bf16)fmaxf(c[rr][1][j] + (float)xr[4 + j], 0.0f);
            }
            *reinterpret_cast<bf16x8*>(
                outb + ((size_t)(y0 + y + 4) * AS + x0 + seg + col + 4) * 32 + g * 8) = o;
        }
    }
}

// ---------------------------------------------------------------------------
// FUSED core_pred + final_conv v3: BOTH phase loops pinned with
// `#pragma unroll 1` (r16's spill = compiler unrolling the chunk loop ->
// 4 overlapping Wf[9][2] live ranges, and partially unrolling the u-loop).
// Wcore in LDS. LDS 144640 B.
// ---------------------------------------------------------------------------
__global__ __launch_bounds__(512, 1) void core_final(
    const bf16* __restrict__ m, const bf16* __restrict__ framesP,
    const float* __restrict__ tauP, const bf16* __restrict__ WcoreG,
    const float* __restrict__ bCore, const bf16* __restrict__ Wfin,
    const float* __restrict__ bfin, float* __restrict__ out) {
    extern __shared__ char smem[];
    bf16* fr    = (bf16*)smem;             // 676 rec x 32 el, slot c^((rec>>1)&3)
    bf16* predt = (bf16*)(smem + 43264);   // 324 rec x 128 el, slot s16^(px&7)
    bf16* Wc    = (bf16*)(smem + 126208);  // [tap 9][n 32][c 32] = 18432 B
    const int x0 = blockIdx.x * 16, y0 = blockIdx.y * 16, b = blockIdx.z;
    const int tid = threadIdx.x;
    const int lane = tid & 63, wv = tid >> 6;
    const int col = lane & 15, g = lane >> 4;

    // stage Wcore into LDS
    for (int i = tid; i < 1152; i += 512)
        *reinterpret_cast<bf16x8*>(Wc + i * 8) =
            *reinterpret_cast<const bf16x8*>(WcoreG + i * 8);

    // stage frames 26x26 (halo 5), bounds-checked, swizzled slots
    const bf16* fb = framesP + (size_t)b * APX * 32;
    for (int i = tid; i < 2704; i += 512) {
        int rec = i >> 2, c = i & 3;
        int yy = rec / 26, xx = rec % 26;
        int gy = y0 + yy - 5, gx = x0 + xx - 5;
        bf16x8 v = bzero8();
        if ((unsigned)gy < HH && (unsigned)gx < WW)
            v = *reinterpret_cast<const bf16x8*>(
                fb + ((size_t)(gy + 4) * AS + gx + 4) * 32 + c * 8);
        *reinterpret_cast<bf16x8*>(fr + rec * 32 + (c ^ ((rec >> 1) & 3)) * 8) = v;
    }

    float t8[8];
    #pragma unroll
    for (int k = 0; k < 8; ++k) t8[k] = tauP[g * 8 + k];
    __syncthreads();

    // ---- pred phase: 36 units = 18 rows x 2 col-groups ----
    const bf16* mb = m + (size_t)b * APX * 32;
    #pragma unroll 1
    for (int u = wv; u < 36; u += 8) {
        const int pr = u >> 1, cg = u & 1;
        const int pc = cg * 2 + col;              // 0..15 / 2..17
        const int gy = y0 - 1 + pr, gx = x0 - 1 + pc;

        bf16x8 Bv = *reinterpret_cast<const bf16x8*>(
            mb + ((size_t)(gy + 4) * AS + gx + 4) * 32 + g * 8);
        #pragma unroll
        for (int k = 0; k < 8; ++k)
            Bv[k] = (bf16)fmaxf((float)Bv[k] - t8[k], 0.0f);

        float acc[4][8];
        #pragma unroll
        for (int r = 0; r < 4; ++r)
            #pragma unroll
            for (int k = 0; k < 8; ++k) acc[r][k] = 0.0f;

        #pragma unroll
        for (int dy = 0; dy < 3; ++dy) {
            float core[3][8];
            #pragma unroll
            for (int dx = 0; dx < 3; ++dx) {
                const int tap = dy * 3 + dx;
                bf16x8 A0 = *reinterpret_cast<const bf16x8*>(
                    Wc + tap * 1024 + col * 32 + g * 8);
                bf16x8 A1 = *reinterpret_cast<const bf16x8*>(
                    Wc + tap * 1024 + (16 + col) * 32 + g * 8);
                f32x4 c0 = *reinterpret_cast<const f32x4*>(bCore + tap * 32 + 4 * g);
                f32x4 c1 = *reinterpret_cast<const f32x4*>(bCore + tap * 32 + 16 + 4 * g);
                c0 = __builtin_amdgcn_mfma_f32_16x16x32_bf16(A0, Bv, c0, 0, 0, 0);
                c1 = __builtin_amdgcn_mfma_f32_16x16x32_bf16(A1, Bv, c1, 0, 0, 0);
                #pragma unroll
                for (int j = 0; j < 4; ++j) {
                    core[dx][j]     = c0[j];
                    core[dx][4 + j] = c1[j];
                }
            }
            #pragma unroll
            for (int R = 1; R <= 4; ++R) {
                const int fy = pr + 4 + (dy - 1) * R;
                #pragma unroll
                for (int dx = 0; dx < 3; ++dx) {
                    const int fx = pc + 4 + (dx - 1) * R;
                    const int rec = fy * 26 + fx;
                    bf16x8 f8 = *reinterpret_cast<const bf16x8*>(
                        fr + rec * 32 + (g ^ ((rec >> 1) & 3)) * 8);
                    #pragma unroll
                    for (int k = 0; k < 8; ++k)
                        acc[R - 1][k] += core[dx][k] * (float)f8[k];
                }
            }
        }

        const bool oob = ((unsigned)gy >= HH) || ((unsigned)gx >= WW);
        const int px = pr * 18 + pc;
        #pragma unroll
        for (int r = 0; r < 4; ++r) {
            bf16x8 o;
            #pragma unroll
            for (int k = 0; k < 8; ++k) o[k] = oob ? (bf16)0.0f : (bf16)acc[r][k];
            *reinterpret_cast<bf16x8*>(
                predt + px * 128 + ((r * 4 + g) ^ (px & 7)) * 8) = o;
        }
    }
    __syncthreads();

    // ---- final phase: R2 row-blocks, pred entirely in LDS ----
    const int rb = wv * 2;
    f32x4 a[2][2];
    {
        f32x4 b0 = *reinterpret_cast<const f32x4*>(bfin + 4 * g);
        f32x4 b1 = *reinterpret_cast<const f32x4*>(bfin + 16 + 4 * g);
        #pragma unroll
        for (int rr = 0; rr < 2; ++rr) { a[rr][0] = b0; a[rr][1] = b1; }
    }

    #pragma unroll 1
    for (int chunk = 0; chunk < 4; ++chunk) {
        bf16x8 Wf[9][2];
        #pragma unroll
        for (int tap = 0; tap < 9; ++tap) {
            Wf[tap][0] = *reinterpret_cast<const bf16x8*>(
                Wfin + chunk * 9216 + tap * 1024 + col * 32 + g * 8);
            Wf[tap][1] = *reinterpret_cast<const bf16x8*>(
                Wfin + chunk * 9216 + tap * 1024 + (16 + col) * 32 + g * 8);
        }
        #pragma unroll
        for (int d = 0; d < 4; ++d) {
            #pragma unroll
            for (int dx = 0; dx < 3; ++dx) {
                const int px = (rb + d) * 18 + col + dx;
                bf16x8 Bf = *reinterpret_cast<const bf16x8*>(
                    predt + px * 128 + (((chunk * 4 + g) ^ (px & 7))) * 8);
                #pragma unroll
                for (int rr = 0; rr < 2; ++rr) {
                    if (rr <= d && d - rr <= 2) {
                        const int tap = (d - rr) * 3 + dx;
                        a[rr][0] = __builtin_amdgcn_mfma_f32_16x16x32_bf16(Wf[tap][0], Bf, a[rr][0], 0, 0, 0);
                        a[rr][1] = __builtin_amdgcn_mfma_f32_16x16x32_bf16(Wf[tap][1], Bf, a[rr][1], 0, 0, 0);
                    }
                }
            }
        }
    }

    #pragma unroll
    for (int rr = 0; rr < 2; ++rr) {
        const int y = y0 + rb + rr;
        const int x = x0 + col;
        #pragma unroll
        for (int j = 0; j < 4; ++j) {
            out[(size_t)(b * 32 + 4 * g + j) * NPIX + (size_t)y * WW + x] = a[rr][0][j];
            out[(size_t)(b * 32 + 16 + 4 * g + j) * NPIX + (size_t)y * WW + x] = a[rr][1][j];
        }
    }
}

// ---------------------------------------------------------------------------
extern "C" void kernel_launch(void* const* d_in, const int* in_sizes, int n_in,
                              void* d_out, int out_size, void* d_ws, size_t ws_size,
                              hipStream_t stream) {
    const float* input    = (const float*)d_in[0];
    const float* wconv    = (const float*)d_in[1];
    const float* bconv    = (const float*)d_in[2];
    const float* bn_gamma = (const float*)d_in[3];
    const float* bn_beta  = (const float*)d_in[4];
    const float* bn_mean  = (const float*)d_in[5];
    const float* bn_var   = (const float*)d_in[6];
    const float* tau      = (const float*)d_in[7];
    const float* w_outc   = (const float*)d_in[8];
    const float* b_outc   = (const float*)d_in[9];
    const float* w_final  = (const float*)d_in[10];
    const float* b_final  = (const float*)d_in[11];
    float* out = (float*)d_out;

    char* ws = (char*)d_ws;
    bf16*  Wres  = (bf16*)(ws);                        // [0, 147456)
    float* Bres  = (float*)(ws + 147456);              // [147456, 148480)
    bf16*  Wcore = (bf16*)(ws + 148480);               // [148480, 166912)
    bf16*  Wfin  = (bf16*)(ws + 166912);               // [166912, 240640)
    float* bCore = (float*)(ws + 240640);              // [240640, 241792)
    float* tauP  = (float*)(ws + 241792);              // [241792, 241920) + pad
    const size_t ACTB = (size_t)APX * 32 * 2;
    bf16*  in0b  = (bf16*)(ws + 245760);
    bf16*  actA  = (bf16*)(ws + 245760 + 4 * ACTB);
    bf16*  actB  = (bf16*)(ws + 245760 + 8 * ACTB);

    hipFuncSetAttribute(reinterpret_cast<const void*>(&resblock_v4),
                        hipFuncAttributeMaxDynamicSharedMemorySize, 105024);
    hipFuncSetAttribute(reinterpret_cast<const void*>(&core_final),
                        hipFuncAttributeMaxDynamicSharedMemorySize, 144640);

    prep_in<<<1024, 256, 0, stream>>>(input, in0b);
    zero_halo<<<195, 256, 0, stream>>>(in0b, actA, actB);
    fold_w<<<471, 256, 0, stream>>>(wconv, bconv, bn_gamma, bn_beta, bn_mean, bn_var,
                                    w_outc, b_outc, w_final, tau,
                                    Wres, Bres, Wcore, Wfin, bCore, tauP);

    dim3 gridr(4, 32, 4), blkr(512);
    resblock_v4<<<gridr, blkr, 105024, stream>>>(in0b, Wres + 0 * 9216, Wres + 1 * 9216,
                                                 Bres + 0,  Bres + 32,  actA);
    resblock_v4<<<gridr, blkr, 105024, stream>>>(actA, Wres + 2 * 9216, Wres + 3 * 9216,
                                                 Bres + 64, Bres + 96,  actB);
    resblock_v4<<<gridr, blkr, 105024, stream>>>(actB, Wres + 4 * 9216, Wres + 5 * 9216,
                                                 Bres + 128, Bres + 160, actA);
    resblock_v4<<<gridr, blkr, 105024, stream>>>(actA, Wres + 6 * 9216, Wres + 7 * 9216,
                                                 Bres + 192, Bres + 224, actB);

    dim3 gridcf(16, 16, 4);
    core_final<<<gridcf, dim3(512), 144640, stream>>>(actB, in0b, tauP, Wcore, bCore,
                                                      Wfin, b_final, out);
}

// Round 18
// 167.920 us; speedup vs baseline: 2.6216x; 2.6216x over previous
//
#include <hip/hip_runtime.h>

typedef __bf16 bf16;
typedef __attribute__((ext_vector_type(8))) __bf16 bf16x8;
typedef __attribute__((ext_vector_type(4))) float f32x4;

#define HH 256
#define WW 256
#define BB 4
#define NPIX 65536
#define AS 264              // act stride (halo 4)
#define APX 69696           // AS*AS
#define PS 258              // pred stride (halo 1)
#define PPX 66564           // PS*PS

#define GLOAD16(SRC, DST) __builtin_amdgcn_global_load_lds( \
    (const __attribute__((address_space(1))) void*)(SRC),   \
    (__attribute__((address_space(3))) void*)(DST), 16, 0, 0)

__device__ inline bf16x8 bzero8() {
    bf16x8 v;
    #pragma unroll
    for (int i = 0; i < 8; ++i) v[i] = (bf16)0.0f;
    return v;
}

// slot s <-> true channel ch(s)
__device__ inline int chof(int s) {
    return 4 * (s >> 3) + 16 * ((s >> 2) & 1) + (s & 3);
}

// ---------------------------------------------------------------------------
// input NCHW fp32 -> in0b (haloed NHWC bf16, SLOT-permuted channels)
// ---------------------------------------------------------------------------
__global__ __launch_bounds__(256) void prep_in(const float* __restrict__ in,
                                               bf16* __restrict__ outP) {
    int p = blockIdx.x * 256 + threadIdx.x;
    int b = p >> 16, rem = p & 65535;
    int y = rem >> 8, x = rem & 255;
    float ch[32];
    #pragma unroll
    for (int c = 0; c < 32; ++c)
        ch[c] = in[(size_t)(b * 32 + c) * NPIX + rem];
    bf16* o = outP + ((size_t)b * APX + (size_t)(y + 4) * AS + x + 4) * 32;
    #pragma unroll
    for (int g = 0; g < 4; ++g) {
        bf16x8 w;
        #pragma unroll
        for (int j = 0; j < 4; ++j) {
            w[j]     = (bf16)ch[4 * g + j];
            w[4 + j] = (bf16)ch[16 + 4 * g + j];
        }
        *reinterpret_cast<bf16x8*>(o + g * 8) = w;
    }
}

// ---------------------------------------------------------------------------
// zero the halos of in0b/actA/actB (4160 px each per batch) and pred (1028)
// ---------------------------------------------------------------------------
__global__ __launch_bounds__(256) void zero_halo(bf16* __restrict__ in0b,
                                                 bf16* __restrict__ actA,
                                                 bf16* __restrict__ actB,
                                                 bf16* __restrict__ pred) {
    int i = blockIdx.x * 256 + threadIdx.x;
    const int NA = 3 * 4 * 4160;
    if (i < NA) {
        int buf = i / (4 * 4160), r = i % (4 * 4160);
        int b = r / 4160, k = r % 4160;
        int y, x;
        if (k < 2112) { int rr = k / 264; y = rr < 4 ? rr : 256 + rr; x = k % 264; }
        else { int j = k - 2112; y = 4 + j / 8; int c8 = j % 8; x = c8 < 4 ? c8 : 256 + c8; }
        bf16* p = (buf == 0 ? in0b : buf == 1 ? actA : actB) +
                  ((size_t)b * APX + (size_t)y * AS + x) * 32;
        #pragma unroll
        for (int cg = 0; cg < 4; ++cg)
            *reinterpret_cast<bf16x8*>(p + cg * 8) = bzero8();
    } else if (i < NA + 4 * 1028) {
        int r = i - NA;
        int b = r / 1028, k = r % 1028;
        int y, x;
        if (k < 516) { int rr = k / 258; y = rr ? 257 : 0; x = k % 258; }
        else { int j = k - 516; y = 1 + j / 2; x = (j & 1) ? 257 : 0; }
        bf16* p = pred + ((size_t)b * PPX + (size_t)y * PS + x) * 128;
        #pragma unroll
        for (int cg = 0; cg < 16; ++cg)
            *reinterpret_cast<bf16x8*>(p + cg * 8) = bzero8();
    }
}

// ---------------------------------------------------------------------------
// Fold BN into conv weights. All activation ci dims are SLOT-permuted.
// ---------------------------------------------------------------------------
__global__ void fold_w(const float* __restrict__ wconv, const float* __restrict__ bconv,
                       const float* __restrict__ g, const float* __restrict__ beta,
                       const float* __restrict__ mu, const float* __restrict__ var,
                       const float* __restrict__ w_outc, const float* __restrict__ b_outc,
                       const float* __restrict__ w_final, const float* __restrict__ tau,
                       bf16* __restrict__ Wres, float* __restrict__ Bres,
                       bf16* __restrict__ Wcore, bf16* __restrict__ Wfin,
                       float* __restrict__ bCore, float* __restrict__ tauP) {
    int idx = blockIdx.x * 256 + threadIdx.x;
    if (idx < 73728) {
        int l = idx / 9216, r = idx % 9216;
        int tap = r >> 10, co = (r >> 5) & 31, ci = chof(r & 31);
        float s = g[l * 32 + co] * rsqrtf(var[l * 32 + co] + 1e-5f);
        Wres[idx] = (bf16)(wconv[l * 9216 + (co * 32 + ci) * 9 + tap] * s);
    } else if (idx < 73984) {
        int i = idx - 73728;
        float s = g[i] * rsqrtf(var[i] + 1e-5f);
        Bres[i] = (bconv[i] - mu[i]) * s + beta[i];
    } else if (idx < 83200) {
        int r = idx - 73984;
        int tap = r >> 10, nn = (r >> 5) & 31, ci = chof(r & 31);
        Wcore[r] = (bf16)w_outc[(nn * 9 + tap) * 32 + ci];
    } else if (idx < 120064) {
        int r = idx - 83200;
        int chunk = r / 9216, r2 = r % 9216;
        int tap = r2 >> 10, co = (r2 >> 5) & 31, n = chof(r2 & 31);
        Wfin[r] = (bf16)w_final[(size_t)(co * 128 + chunk * 32 + n) * 9 + tap];
    } else if (idx < 120352) {
        int r = idx - 120064;       // tap*32 + n
        int tap = r >> 5, n = r & 31;
        bCore[r] = b_outc[n * 9 + tap];
    } else if (idx < 120384) {
        int s = idx - 120352;
        tauP[s] = tau[chof(s)];
    }
}

// ---------------------------------------------------------------------------
// Fused residual block v4 (r14-proven) + XCD-aware block swizzle (T1).
// 1D grid of 512 blocks; wg = (bid&7)*64 + bid>>3 gives each XCD a
// contiguous tile range (y-neighbors share halo rows in its L2).
// ---------------------------------------------------------------------------
__global__ __launch_bounds__(512) void resblock_v4(
    const bf16* __restrict__ in, const bf16* __restrict__ W1,
    const bf16* __restrict__ W2, const float* __restrict__ B1,
    const float* __restrict__ B2, bf16* __restrict__ out) {
    extern __shared__ char smem[];
    bf16* xs = (bf16*)smem;             // [12][68] records, 64 B each, swizzled
    bf16* hs = (bf16*)(smem + 52224);   // [10][66] records, pitch 40 el
    const int bid = blockIdx.x;
    const int wg = (bid & 7) * 64 + (bid >> 3);
    const int x0 = (wg & 3) * 64, y0 = ((wg >> 2) & 31) * 8, b = wg >> 7;
    const int tid = threadIdx.x;
    const int lane = tid & 63, wv = tid >> 6;
    const int col = lane & 15, g = lane >> 4;
    const bf16* inb = in + (size_t)b * APX * 32;

    for (int gi = wv; gi < 51; gi += 8) {
        int i = gi * 64 + lane;
        int px = i >> 2, s = i & 3;
        int yy = px / 68, xx = px % 68;
        int gsl = s ^ ((px >> 1) & 3);
        const bf16* src = inb + ((size_t)(y0 + yy + 2) * AS + x0 + xx + 2) * 32 + gsl * 8;
        GLOAD16(src, smem + gi * 1024);
    }

    bf16x8 Wf[9][2];
    #pragma unroll
    for (int tap = 0; tap < 9; ++tap) {
        Wf[tap][0] = *reinterpret_cast<const bf16x8*>(W1 + tap * 1024 + col * 32 + g * 8);
        Wf[tap][1] = *reinterpret_cast<const bf16x8*>(W1 + tap * 1024 + (16 + col) * 32 + g * 8);
    }
    f32x4 bb0 = *reinterpret_cast<const f32x4*>(B1 + 4 * g);
    f32x4 bb1 = *reinterpret_cast<const f32x4*>(B1 + 16 + 4 * g);
    __syncthreads();

    for (int id = wv; id < 15; id += 8) {
        int u = id / 5, s5 = id % 5;
        int rb = u * 4; if (rb > 6) rb = 6;
        int off = s5 * 16; if (off > 50) off = 50;
        f32x4 c[4][2];
        #pragma unroll
        for (int rr = 0; rr < 4; ++rr) { c[rr][0] = bb0; c[rr][1] = bb1; }
        #pragma unroll
        for (int d = 0; d < 6; ++d) {
            #pragma unroll
            for (int dx = 0; dx < 3; ++dx) {
                const int px = (rb + d) * 68 + off + col + dx;
                bf16x8 Bf = *reinterpret_cast<const bf16x8*>(
                    xs + px * 32 + (g ^ ((px >> 1) & 3)) * 8);
                #pragma unroll
                for (int rr = 0; rr < 4; ++rr) {
                    if (rr <= d && d - rr <= 2) {
                        const int tap = (d - rr) * 3 + dx;
                        c[rr][0] = __builtin_amdgcn_mfma_f32_16x16x32_bf16(Wf[tap][0], Bf, c[rr][0], 0, 0, 0);
                        c[rr][1] = __builtin_amdgcn_mfma_f32_16x16x32_bf16(Wf[tap][1], Bf, c[rr][1], 0, 0, 0);
                    }
                }
            }
        }
        #pragma unroll
        for (int rr = 0; rr < 4; ++rr) {
            bf16x8 o;
            #pragma unroll
            for (int j = 0; j < 4; ++j) {
                o[j]     = (bf16)fmaxf(c[rr][0][j], 0.0f);
                o[4 + j] = (bf16)fmaxf(c[rr][1][j], 0.0f);
            }
            const int hy = y0 + rb + rr - 1;
            const int hx = x0 + off + col - 1;
            if ((unsigned)hy >= HH || (unsigned)hx >= WW) o = bzero8();
            *reinterpret_cast<bf16x8*>(hs + ((rb + rr) * 66 + off + col) * 40 + g * 8) = o;
        }
    }

    #pragma unroll
    for (int tap = 0; tap < 9; ++tap) {
        Wf[tap][0] = *reinterpret_cast<const bf16x8*>(W2 + tap * 1024 + col * 32 + g * 8);
        Wf[tap][1] = *reinterpret_cast<const bf16x8*>(W2 + tap * 1024 + (16 + col) * 32 + g * 8);
    }
    bb0 = *reinterpret_cast<const f32x4*>(B2 + 4 * g);
    bb1 = *reinterpret_cast<const f32x4*>(B2 + 16 + 4 * g);
    __syncthreads();

    {
        const int rb2 = (wv >> 2) * 4, seg = (wv & 3) * 16;
        f32x4 c[4][2];
        #pragma unroll
        for (int rr = 0; rr < 4; ++rr) { c[rr][0] = bb0; c[rr][1] = bb1; }
        #pragma unroll
        for (int d = 0; d < 6; ++d) {
            #pragma unroll
            for (int dx = 0; dx < 3; ++dx) {
                bf16x8 Bf = *reinterpret_cast<const bf16x8*>(
                    hs + ((rb2 + d) * 66 + seg + col + dx) * 40 + g * 8);
                #pragma unroll
                for (int rr = 0; rr < 4; ++rr) {
                    if (rr <= d && d - rr <= 2) {
                        const int tap = (d - rr) * 3 + dx;
                        c[rr][0] = __builtin_amdgcn_mfma_f32_16x16x32_bf16(Wf[tap][0], Bf, c[rr][0], 0, 0, 0);
                        c[rr][1] = __builtin_amdgcn_mfma_f32_16x16x32_bf16(Wf[tap][1], Bf, c[rr][1], 0, 0, 0);
                    }
                }
            }
        }
        bf16* outb = out + (size_t)b * APX * 32;
        #pragma unroll
        for (int rr = 0; rr < 4; ++rr) {
            const int y = rb2 + rr;
            const int pxr = (y + 2) * 68 + seg + col + 2;
            bf16x8 xr = *reinterpret_cast<const bf16x8*>(
                xs + pxr * 32 + (g ^ ((pxr >> 1) & 3)) * 8);
            bf16x8 o;
            #pragma unroll
            for (int j = 0; j < 4; ++j) {
                o[j]     = (bf16)fmaxf(c[rr][0][j] + (float)xr[j], 0.0f);
                o[4 + j] = (bf16)fmaxf(c[rr][1][j] + (float)xr[4 + j], 0.0f);
            }
            *reinterpret_cast<bf16x8*>(
                outb + ((size_t)(y0 + y + 4) * AS + x0 + seg + col + 4) * 32 + g * 8) = o;
        }
    }
}

// ---------------------------------------------------------------------------
// final conv3x3 (128->32) v6 (r14-proven) + XCD swizzle: dy-blocked R4,
// tile 64x8, 512 thr, 2-phase double-buffered gload staging.
// ---------------------------------------------------------------------------
__global__ __launch_bounds__(512) void final_conv_v6(
    const bf16* __restrict__ pred, const bf16* __restrict__ Wfin,
    const float* __restrict__ bfin, float* __restrict__ out) {
    extern __shared__ char smem[];      // 2 x 43008 B
    const int bid = blockIdx.x;
    const int wg = (bid & 7) * 64 + (bid >> 3);
    const int x0 = (wg & 3) * 64, y0 = ((wg >> 2) & 31) * 8, b = wg >> 7;
    const int tid = threadIdx.x;
    const int lane = tid & 63, wv = tid >> 6;
    const int col = lane & 15, g = lane >> 4;
    const bf16* pb = pred + (size_t)b * PPX * 128;

    auto stage = [&](int c, int bi) {
        for (int gi = wv; gi < 42; gi += 8) {       // 660 px x 4 slots, padded
            int i = gi * 64 + lane;
            int px = i >> 2; if (px > 659) px = 659;
            int s = i & 3;
            int yy = px / 66, xx = px % 66;
            int gsl = s ^ ((px >> 1) & 3);
            const bf16* src = pb + ((size_t)(y0 + yy) * PS + x0 + xx) * 128 + c * 32 + gsl * 8;
            GLOAD16(src, smem + bi * 43008 + gi * 1024);
        }
    };

    const int rb = (wv >> 2) * 4, seg = (wv & 3) * 16;
    f32x4 a[4][2];
    {
        f32x4 b0 = *reinterpret_cast<const f32x4*>(bfin + 4 * g);
        f32x4 b1 = *reinterpret_cast<const f32x4*>(bfin + 16 + 4 * g);
        #pragma unroll
        for (int rr = 0; rr < 4; ++rr) { a[rr][0] = b0; a[rr][1] = b1; }
    }

    stage(0, 0);
    __syncthreads();

    for (int chunk = 0; chunk < 4; ++chunk) {
        const int cur = chunk & 1;
        bf16x8 Wf[9][2];
        #pragma unroll
        for (int tap = 0; tap < 9; ++tap) {
            Wf[tap][0] = *reinterpret_cast<const bf16x8*>(
                Wfin + chunk * 9216 + tap * 1024 + col * 32 + g * 8);
            Wf[tap][1] = *reinterpret_cast<const bf16x8*>(
                Wfin + chunk * 9216 + tap * 1024 + (16 + col) * 32 + g * 8);
        }
        if (chunk < 3) stage(chunk + 1, cur ^ 1);

        const bf16* pt = (const bf16*)(smem + cur * 43008);
        #pragma unroll
        for (int d = 0; d < 6; ++d) {
            #pragma unroll
            for (int dx = 0; dx < 3; ++dx) {
                const int px = (rb + d) * 66 + seg + col + dx;
                bf16x8 Bf = *reinterpret_cast<const bf16x8*>(
                    pt + px * 32 + (g ^ ((px >> 1) & 3)) * 8);
                #pragma unroll
                for (int rr = 0; rr < 4; ++rr) {
                    if (rr <= d && d - rr <= 2) {
                        const int tap = (d - rr) * 3 + dx;
                        a[rr][0] = __builtin_amdgcn_mfma_f32_16x16x32_bf16(Wf[tap][0], Bf, a[rr][0], 0, 0, 0);
                        a[rr][1] = __builtin_amdgcn_mfma_f32_16x16x32_bf16(Wf[tap][1], Bf, a[rr][1], 0, 0, 0);
                    }
                }
            }
        }
        __syncthreads();
    }

    #pragma unroll
    for (int rr = 0; rr < 4; ++rr) {
        const int y = y0 + rb + rr;
        const int x = x0 + seg + col;
        #pragma unroll
        for (int j = 0; j < 4; ++j) {
            out[(size_t)(b * 32 + 4 * g + j) * NPIX + (size_t)y * WW + x] = a[rr][0][j];
            out[(size_t)(b * 32 + 16 + 4 * g + j) * NPIX + (size_t)y * WW + x] = a[rr][1][j];
        }
    }
}

// ---------------------------------------------------------------------------
// core_pred v4 (haloed strides, r14-proven): swapped-operand core MFMA.
// ---------------------------------------------------------------------------
__global__ __launch_bounds__(256, 2) void core_pred_v4(
    const bf16* __restrict__ m, const bf16* __restrict__ framesP,
    const float* __restrict__ tauP, const bf16* __restrict__ WcoreG,
    const float* __restrict__ bCore, bf16* __restrict__ pred) {
    __shared__ bf16 fr[576 * 32];      // [24y][24x][32 slots] = 36864 B
    __shared__ bf16 Wc[9 * 32 * 32];   // [tap][n][c]          = 18432 B
    const int x0 = blockIdx.x * 16, y0 = blockIdx.y * 16, b = blockIdx.z;
    const int tid = threadIdx.x;
    const int lane = tid & 63, wv = tid >> 6;
    const int col = lane & 15, g = lane >> 4;

    for (int i = tid; i < 1152; i += 256)
        *reinterpret_cast<bf16x8*>(Wc + i * 8) =
            *reinterpret_cast<const bf16x8*>(WcoreG + i * 8);
    const bf16* fb = framesP + (size_t)b * APX * 32;
    for (int i = tid; i < 2304; i += 256) {
        int px = i >> 2, cg = i & 3;
        int yy = px / 24, xx = px % 24;
        bf16x8 v = *reinterpret_cast<const bf16x8*>(
            fb + ((size_t)(y0 + yy) * AS + x0 + xx) * 32 + cg * 8);
        *reinterpret_cast<bf16x8*>(fr + px * 32 + cg * 8) = v;
    }
    float t8[8];
    #pragma unroll
    for (int k = 0; k < 8; ++k) t8[k] = tauP[g * 8 + k];
    __syncthreads();

    const bf16* mb = m + (size_t)b * APX * 32;
    bf16* pb = pred + (size_t)b * PPX * 128;

    #pragma unroll 1
    for (int uu = 0; uu < 4; ++uu) {
        const int yl = wv * 4 + uu;
        const int y = y0 + yl;

        bf16x8 Bv = *reinterpret_cast<const bf16x8*>(
            mb + ((size_t)(y + 4) * AS + x0 + col + 4) * 32 + g * 8);
        #pragma unroll
        for (int k = 0; k < 8; ++k)
            Bv[k] = (bf16)fmaxf((float)Bv[k] - t8[k], 0.0f);

        float acc[4][8];
        #pragma unroll
        for (int r = 0; r < 4; ++r)
            #pragma unroll
            for (int k = 0; k < 8; ++k) acc[r][k] = 0.0f;

        #pragma unroll
        for (int dy = 0; dy < 3; ++dy) {
            float core[3][8];
            #pragma unroll
            for (int dx = 0; dx < 3; ++dx) {
                const int tap = dy * 3 + dx;
                bf16x8 A0 = *reinterpret_cast<const bf16x8*>(
                    Wc + tap * 1024 + col * 32 + g * 8);
                bf16x8 A1 = *reinterpret_cast<const bf16x8*>(
                    Wc + tap * 1024 + (16 + col) * 32 + g * 8);
                f32x4 c0 = *reinterpret_cast<const f32x4*>(bCore + tap * 32 + 4 * g);
                f32x4 c1 = *reinterpret_cast<const f32x4*>(bCore + tap * 32 + 16 + 4 * g);
                c0 = __builtin_amdgcn_mfma_f32_16x16x32_bf16(A0, Bv, c0, 0, 0, 0);
                c1 = __builtin_amdgcn_mfma_f32_16x16x32_bf16(A1, Bv, c1, 0, 0, 0);
                #pragma unroll
                for (int j = 0; j < 4; ++j) {
                    core[dx][j]     = c0[j];
                    core[dx][4 + j] = c1[j];
                }
            }
            #pragma unroll
            for (int r = 1; r <= 4; ++r) {
                const int row = yl + 4 + (dy - 1) * r;
                #pragma unroll
                for (int dx = 0; dx < 3; ++dx) {
                    const int cc = col + 4 + (dx - 1) * r;
                    bf16x8 f8 = *reinterpret_cast<const bf16x8*>(
                        fr + (row * 24 + cc) * 32 + g * 8);
                    #pragma unroll
                    for (int k = 0; k < 8; ++k)
                        acc[r - 1][k] += core[dx][k] * (float)f8[k];
                }
            }
        }

        #pragma unroll
        for (int r = 0; r < 4; ++r) {
            bf16x8 o;
            #pragma unroll
            for (int k = 0; k < 8; ++k) o[k] = (bf16)acc[r][k];
            *reinterpret_cast<bf16x8*>(
                pb + ((size_t)(y + 1) * PS + x0 + col + 1) * 128 + r * 32 + g * 8) = o;
        }
    }
}

// ---------------------------------------------------------------------------
extern "C" void kernel_launch(void* const* d_in, const int* in_sizes, int n_in,
                              void* d_out, int out_size, void* d_ws, size_t ws_size,
                              hipStream_t stream) {
    const float* input    = (const float*)d_in[0];
    const float* wconv    = (const float*)d_in[1];
    const float* bconv    = (const float*)d_in[2];
    const float* bn_gamma = (const float*)d_in[3];
    const float* bn_beta  = (const float*)d_in[4];
    const float* bn_mean  = (const float*)d_in[5];
    const float* bn_var   = (const float*)d_in[6];
    const float* tau      = (const float*)d_in[7];
    const float* w_outc   = (const float*)d_in[8];
    const float* b_outc   = (const float*)d_in[9];
    const float* w_final  = (const float*)d_in[10];
    const float* b_final  = (const float*)d_in[11];
    float* out = (float*)d_out;

    char* ws = (char*)d_ws;
    bf16*  Wres  = (bf16*)(ws);                        // [0, 147456)
    float* Bres  = (float*)(ws + 147456);              // [147456, 148480)
    bf16*  Wcore = (bf16*)(ws + 148480);               // [148480, 166912)
    bf16*  Wfin  = (bf16*)(ws + 166912);               // [166912, 240640)
    float* bCore = (float*)(ws + 240640);              // [240640, 241792)
    float* tauP  = (float*)(ws + 241792);              // [241792, 241920) + pad
    const size_t ACTB = (size_t)APX * 32 * 2;
    bf16*  in0b  = (bf16*)(ws + 245760);
    bf16*  actA  = (bf16*)(ws + 245760 + 4 * ACTB);
    bf16*  actB  = (bf16*)(ws + 245760 + 8 * ACTB);
    bf16*  pred  = (bf16*)(ws + 245760 + 12 * ACTB);

    hipFuncSetAttribute(reinterpret_cast<const void*>(&resblock_v4),
                        hipFuncAttributeMaxDynamicSharedMemorySize, 105024);
    hipFuncSetAttribute(reinterpret_cast<const void*>(&final_conv_v6),
                        hipFuncAttributeMaxDynamicSharedMemorySize, 86016);

    prep_in<<<1024, 256, 0, stream>>>(input, in0b);
    zero_halo<<<212, 256, 0, stream>>>(in0b, actA, actB, pred);
    fold_w<<<471, 256, 0, stream>>>(wconv, bconv, bn_gamma, bn_beta, bn_mean, bn_var,
                                    w_outc, b_outc, w_final, tau,
                                    Wres, Bres, Wcore, Wfin, bCore, tauP);

    dim3 blkr(512);
    resblock_v4<<<512, blkr, 105024, stream>>>(in0b, Wres + 0 * 9216, Wres + 1 * 9216,
                                               Bres + 0,  Bres + 32,  actA);
    resblock_v4<<<512, blkr, 105024, stream>>>(actA, Wres + 2 * 9216, Wres + 3 * 9216,
                                               Bres + 64, Bres + 96,  actB);
    resblock_v4<<<512, blkr, 105024, stream>>>(actB, Wres + 4 * 9216, Wres + 5 * 9216,
                                               Bres + 128, Bres + 160, actA);
    resblock_v4<<<512, blkr, 105024, stream>>>(actA, Wres + 6 * 9216, Wres + 7 * 9216,
                                               Bres + 192, Bres + 224, actB);

    dim3 gridp(16, 16, 4);
    core_pred_v4<<<gridp, dim3(256), 0, stream>>>(actB, in0b, tauP, Wcore, bCore, pred);

    final_conv_v6<<<512, dim3(512), 86016, stream>>>(pred, Wfin, b_final, out);
}